// Round 1
// baseline (899.794 us; speedup 1.0000x reference)
//
#include <hip/hip_runtime.h>

// Problem: N=1024, D=32, IN_F=128, OUT_F=128
//   f      = tanh(u@K + b)                  (N,128)            -> out[0 ..)
//   dfdx   = dsig * (dudx@K)                (N,32,128)         -> out[131072 ..)
//   d2fd2x = d2sig*A_d*A_e + dsig*(d2ud2x@K) (N,32,32,128)     -> out[4325376 ..)
// Strategy: bf16 MFMA (16x16x32) for both GEMMs (harness threshold is
// bf16-grade), fused epilogues, f32 in/out. HBM-bound: ~1.1 GB traffic.
//
// Workspace layout (floats):
//   [0          .. 131072)   dsig
//   [131072     .. 262144)   d2sig
//   [262144     .. 270336)   Kt as bf16 (16384 ushorts = 32 KB)
//   [270336     .. 4464640)  A = dudx@K (f32)
// Needs ws_size >= ~17.9 MB.

typedef __bf16 bf16x8 __attribute__((ext_vector_type(8)));
typedef float f32x4 __attribute__((ext_vector_type(4)));

__device__ __forceinline__ unsigned int pk2bf(float a, float b) {
    unsigned int ua = __builtin_bit_cast(unsigned int, a);
    unsigned int ub = __builtin_bit_cast(unsigned int, b);
    ua = (ua + 0x7FFFu + ((ua >> 16) & 1u)) >> 16;   // RNE
    ub = (ub + 0x7FFFu + ((ub >> 16) & 1u)) >> 16;
    return ua | (ub << 16);
}

// ---------------- k_prep: f, dsig, d2sig ----------------
__global__ __launch_bounds__(256) void k_prep(const float* __restrict__ u,
                                              const float* __restrict__ K,
                                              const float* __restrict__ b,
                                              float* __restrict__ f_out,
                                              float* __restrict__ dsig,
                                              float* __restrict__ d2sig) {
    __shared__ float us[16][128];
    const int t = threadIdx.x;
    const int blk = blockIdx.x;   // 64 blocks x 16 rows
    {
        int row = t >> 4, c = (t & 15) * 8;
        const float4* src = reinterpret_cast<const float4*>(u + (blk * 16 + row) * 128 + c);
        float4 v0 = src[0], v1 = src[1];
        *reinterpret_cast<float4*>(&us[row][c])     = v0;
        *reinterpret_cast<float4*>(&us[row][c + 4]) = v1;
    }
    __syncthreads();
    const int o = t & 127;
    const int rr = (t >> 7) * 8;
    float acc[8] = {0.f, 0.f, 0.f, 0.f, 0.f, 0.f, 0.f, 0.f};
    for (int i = 0; i < 128; ++i) {
        float kv = K[i * 128 + o];
#pragma unroll
        for (int j = 0; j < 8; ++j) acc[j] = fmaf(us[rr + j][i], kv, acc[j]);
    }
    const float bv = b[o];
#pragma unroll
    for (int j = 0; j < 8; ++j) {
        int row = blk * 16 + rr + j;
        float z = acc[j] + bv;
        float fv = tanhf(z);
        float ds = 1.0f - fv * fv;
        f_out[row * 128 + o] = fv;
        dsig[row * 128 + o] = ds;
        d2sig[row * 128 + o] = -2.0f * fv * ds;
    }
}

// ---------------- k_kt: Kt[o][i] = bf16(K[i][o]) ----------------
__global__ __launch_bounds__(128) void k_kt(const float* __restrict__ K,
                                            unsigned short* __restrict__ kt) {
    const int o = blockIdx.x, i = threadIdx.x;
    unsigned int v = __builtin_bit_cast(unsigned int, K[i * 128 + o]);
    v = (v + 0x7FFFu + ((v >> 16) & 1u)) >> 16;
    kt[o * 128 + i] = (unsigned short)v;
}

// ---------------- shared GEMM pieces ----------------
// LDS: Kt 128x(128+8) bf16, X 64x(128+8) bf16; padded stride 136 keeps
// b128 reads/writes at <=2-way bank aliasing (free on gfx950, m136).
#define LPAD 136

__device__ __forceinline__ void stage_kt(const unsigned short* __restrict__ kt,
                                         unsigned short* Ks, int t) {
#pragma unroll
    for (int p = 0; p < 8; ++p) {
        int row = p * 16 + (t >> 4);
        int k0 = (t & 15) * 8;
        uint4 v = *reinterpret_cast<const uint4*>(kt + row * 128 + k0);
        *reinterpret_cast<uint4*>(&Ks[row * LPAD + k0]) = v;
    }
}

__device__ __forceinline__ void stage_x(const float* __restrict__ X, int R0,
                                        unsigned short* Xs, int t) {
#pragma unroll
    for (int p = 0; p < 4; ++p) {
        int row = p * 16 + (t >> 4);
        int c0 = (t & 15) * 8;
        const float4* s = reinterpret_cast<const float4*>(X + (size_t)(R0 + row) * 128 + c0);
        float4 v0 = s[0], v1 = s[1];
        uint4 w;
        w.x = pk2bf(v0.x, v0.y);
        w.y = pk2bf(v0.z, v0.w);
        w.z = pk2bf(v1.x, v1.y);
        w.w = pk2bf(v1.z, v1.w);
        *reinterpret_cast<uint4*>(&Xs[row * LPAD + c0]) = w;
    }
}

// Per-wave 16x128 tile: 8 col-tiles x 4 k-steps of mfma_f32_16x16x32_bf16.
// A-frag: A[m=lane&15][k=q*8+j]; B-frag: Kt[n=16c+lane&15][k=q*8+j];
// C/D: col=lane&15, row=q*4+reg (verified m89/m91).
__device__ __forceinline__ void gemm_tile(const unsigned short* Xs,
                                          const unsigned short* Ks,
                                          int m0l, int q, int l, f32x4 acc[8]) {
#pragma unroll
    for (int s = 0; s < 4; ++s) {
        bf16x8 a = *reinterpret_cast<const bf16x8*>(&Xs[(m0l + l) * LPAD + s * 32 + q * 8]);
#pragma unroll
        for (int c = 0; c < 8; ++c) {
            bf16x8 bf = *reinterpret_cast<const bf16x8*>(&Ks[(c * 16 + l) * LPAD + s * 32 + q * 8]);
            acc[c] = __builtin_amdgcn_mfma_f32_16x16x32_bf16(a, bf, acc[c], 0, 0, 0);
        }
    }
}

// ---------------- k_dfdx: A = dudx@K (->ws), dfdx = dsig*A (->out) ----------------
__global__ __launch_bounds__(256) void k_dfdx(const float* __restrict__ dudx,
                                              const unsigned short* __restrict__ kt,
                                              const float* __restrict__ dsig,
                                              float* __restrict__ wsA,
                                              float* __restrict__ dfdx_out) {
    __shared__ unsigned short Ks[128 * LPAD];
    __shared__ unsigned short Xs[64 * LPAD];
    const int t = threadIdx.x;
    const int R0 = blockIdx.x * 64;   // 512 blocks, rows of (N*D=32768)

    stage_kt(kt, Ks, t);
    stage_x(dudx, R0, Xs, t);
    __syncthreads();

    const int w = t >> 6, lane = t & 63, q = lane >> 4, l = lane & 15;
    f32x4 acc[8];
#pragma unroll
    for (int c = 0; c < 8; ++c) acc[c] = (f32x4){0.f, 0.f, 0.f, 0.f};
    gemm_tile(Xs, Ks, w * 16, q, l, acc);

    const int m0 = R0 + w * 16;
    const int n = m0 >> 5;            // constant across the wave tile
    const float* dsp = dsig + n * 128;
    float* ap = wsA + (size_t)m0 * 128;
    float* dp = dfdx_out + (size_t)m0 * 128;
#pragma unroll
    for (int c = 0; c < 8; ++c) {
        int o = c * 16 + l;
        float ds = dsp[o];
#pragma unroll
        for (int r = 0; r < 4; ++r) {
            int ri = q * 4 + r;
            float a = acc[c][r];
            ap[ri * 128 + o] = a;
            dp[ri * 128 + o] = ds * a;
        }
    }
}

// ---------------- k_hess: d2fd2x = d2sig*Ad*Ae + dsig*(d2ud2x@K) ----------------
__global__ __launch_bounds__(256) void k_hess(const float* __restrict__ X,
                                              const unsigned short* __restrict__ kt,
                                              const float* __restrict__ dsig,
                                              const float* __restrict__ d2sig,
                                              const float* __restrict__ wsA,
                                              float* __restrict__ out_h,
                                              int nchunks) {
    __shared__ unsigned short Ks[128 * LPAD];
    __shared__ unsigned short Xs[64 * LPAD];
    const int t = threadIdx.x;
    stage_kt(kt, Ks, t);

    const int w = t >> 6, lane = t & 63, q = lane >> 4, l = lane & 15;

    for (int chunk = blockIdx.x; chunk < nchunks; chunk += gridDim.x) {
        __syncthreads();              // protect Xs from previous iter's readers
        const int R0 = chunk * 64;    // row in M = N*D*D = 1048576
        stage_x(X, R0, Xs, t);
        __syncthreads();

        f32x4 acc[8];
#pragma unroll
        for (int c = 0; c < 8; ++c) acc[c] = (f32x4){0.f, 0.f, 0.f, 0.f};
        gemm_tile(Xs, Ks, w * 16, q, l, acc);

        // row m = m0 + q*4 + r;  n = m>>10, d = (m>>5)&31, e = m&31
        const int m0 = R0 + w * 16;
        const int n = m0 >> 10;        // constant per wave tile
        const int d = (m0 >> 5) & 31;  // constant per wave tile
        const int e0 = m0 & 31;        // e = e0 + q*4 + r
        const float* dsp = dsig + n * 128;
        const float* d2p = d2sig + n * 128;
        const float* Adp = wsA + (size_t)(n * 32 + d) * 128;
        const float* Aep = wsA + (size_t)(n * 32 + e0) * 128;
        float* outp = out_h + (size_t)m0 * 128;
#pragma unroll
        for (int c = 0; c < 8; ++c) {
            int o = c * 16 + l;
            float ds = dsp[o];
            float tt = d2p[o] * Adp[o];   // d2sig * A_d
#pragma unroll
            for (int r = 0; r < 4; ++r) {
                int ri = q * 4 + r;
                float Ae = Aep[(size_t)ri * 128 + o];
                outp[(size_t)ri * 128 + o] = fmaf(ds, acc[c][r], tt * Ae);
            }
        }
    }
}

extern "C" void kernel_launch(void* const* d_in, const int* in_sizes, int n_in,
                              void* d_out, int out_size, void* d_ws, size_t ws_size,
                              hipStream_t stream) {
    const float* u      = (const float*)d_in[0];
    const float* dudx   = (const float*)d_in[1];
    const float* d2ud2x = (const float*)d_in[2];
    const float* K      = (const float*)d_in[3];
    const float* b      = (const float*)d_in[4];

    float* out = (float*)d_out;
    float* f_out    = out;                       // 1024*128
    float* dfdx_out = out + 131072;              // 1024*32*128
    float* hess_out = out + 131072 + 4194304;    // 1024*32*32*128

    float* ws = (float*)d_ws;
    float* dsig  = ws;                           // 131072
    float* d2sig = ws + 131072;                  // 131072
    unsigned short* kt = (unsigned short*)(ws + 262144);  // 16384 bf16
    float* wsA   = ws + 262144 + 8192;           // 4194304 (A, f32)

    k_prep<<<64, 256, 0, stream>>>(u, K, b, f_out, dsig, d2sig);
    k_kt<<<128, 128, 0, stream>>>(K, kt);
    k_dfdx<<<512, 256, 0, stream>>>(dudx, kt, dsig, wsA, dfdx_out);
    k_hess<<<2048, 256, 0, stream>>>(d2ud2x, kt, dsig, d2sig, wsA, hess_out, 16384);
}